// Round 1
// baseline (485.056 us; speedup 1.0000x reference)
//
#include <hip/hip_runtime.h>
#include <hip/hip_bf16.h>
#include <stdint.h>

#define BATCH 16384
#define DIM   2048
#define DIM2  1024

typedef __attribute__((ext_vector_type(8))) short short8;
typedef __attribute__((ext_vector_type(4))) float f32x4;

__device__ __forceinline__ ushort f2bf(float f) {
  uint32_t u = __float_as_uint(f);
  u += 0x7fffu + ((u >> 16) & 1u);   // RNE
  return (ushort)(u >> 16);
}
__device__ __forceinline__ float bf2f(ushort h) {
  return __uint_as_float(((uint32_t)h) << 16);
}

__device__ __forceinline__ void gload_lds16(const void* g, void* l) {
  __builtin_amdgcn_global_load_lds(
      (__attribute__((address_space(1))) void*)g,
      (__attribute__((address_space(3))) void*)l,
      16, 0, 0);
}

// ---------------- per-row cosine features ----------------
__global__ void __launch_bounds__(256) prep_kernel(const float* __restrict__ vc,
                                                   const float* __restrict__ vd,
                                                   float* __restrict__ feats) {
  int row = blockIdx.x;
  int t = threadIdx.x;
  const float4* c = (const float4*)(vc + (size_t)row * DIM);
  const float4* d = (const float4*)(vd + (size_t)row * DIM);
  float dot = 0.f, c2 = 0.f, d2 = 0.f;
#pragma unroll
  for (int p = 0; p < 2; ++p) {
    float4 a = c[t * 2 + p];
    float4 b = d[t * 2 + p];
    dot += a.x * b.x + a.y * b.y + a.z * b.z + a.w * b.w;
    c2  += a.x * a.x + a.y * a.y + a.z * a.z + a.w * a.w;
    d2  += b.x * b.x + b.y * b.y + b.z * b.z + b.w * b.w;
  }
#pragma unroll
  for (int off = 32; off >= 1; off >>= 1) {
    dot += __shfl_down(dot, off, 64);
    c2  += __shfl_down(c2, off, 64);
    d2  += __shfl_down(d2, off, 64);
  }
  __shared__ float red[3][4];
  int l = t & 63, w = t >> 6;
  if (l == 0) { red[0][w] = dot; red[1][w] = c2; red[2][w] = d2; }
  __syncthreads();
  if (t == 0) {
    float D  = red[0][0] + red[0][1] + red[0][2] + red[0][3];
    float C2 = red[1][0] + red[1][1] + red[1][2] + red[1][3];
    float D2 = red[2][0] + red[2][1] + red[2][2] + red[2][3];
    float nc = fmaxf(sqrtf(C2), 1e-12f);
    float nd = fmaxf(sqrtf(D2), 1e-12f);
    float align = D / (nc * nd);
    float dv = 1.f - align;
    feats[row] = align;
    feats[BATCH + row] = dv;
    feats[2 * BATCH + row] = dv * dv;
  }
}

// ---------------- fp32 -> bf16 convert (A operand) ----------------
__global__ void __launch_bounds__(256) cvt_kernel(const float* __restrict__ in,
                                                  ushort* __restrict__ out) {
  size_t i = (size_t)blockIdx.x * 256 + threadIdx.x;  // 8 elems per thread
  const float4* p = (const float4*)in;
  float4 f0 = p[2 * i], f1 = p[2 * i + 1];
  uint4 u;
  u.x = (uint32_t)f2bf(f0.x) | ((uint32_t)f2bf(f0.y) << 16);
  u.y = (uint32_t)f2bf(f0.z) | ((uint32_t)f2bf(f0.w) << 16);
  u.z = (uint32_t)f2bf(f1.x) | ((uint32_t)f2bf(f1.y) << 16);
  u.w = (uint32_t)f2bf(f1.z) | ((uint32_t)f2bf(f1.w) << 16);
  ((uint4*)out)[i] = u;
}

// ---------------- W [K][N] fp32 -> WT [N][K] bf16 ----------------
__global__ void __launch_bounds__(256) transW(const float* __restrict__ W,
                                              ushort* __restrict__ WT,
                                              int K, int N) {
  __shared__ float tile[32][33];
  int t = threadIdx.x;
  int tx = t & 31, ty = t >> 5;
  int c0 = blockIdx.x * 32, r0 = blockIdx.y * 32;
#pragma unroll
  for (int p = 0; p < 4; ++p)
    tile[ty + p * 8][tx] = W[(size_t)(r0 + ty + p * 8) * N + c0 + tx];
  __syncthreads();
#pragma unroll
  for (int p = 0; p < 4; ++p) {
    int rr = ty + p * 8;  // n offset within tile
    WT[(size_t)(c0 + rr) * K + r0 + tx] = f2bf(tile[tx][rr]);
  }
}

// ---------------- 128x128 bf16 MFMA GEMM (m97 structure) ----------------
// C[M][N] = relu(A[M][K] * BT[N][K]^T + rank3(feats,wex) + bias), bf16 out.
// MODE 1: + feats-rank3 (gemm1).  MODE 2: bias only (gemm2).
template <int MODE, int N>
__global__ void __launch_bounds__(256) gemm_bt(const ushort* __restrict__ A,
                                               const ushort* __restrict__ BT,
                                               ushort* __restrict__ C,
                                               const float* __restrict__ feats,
                                               const float* __restrict__ wex,
                                               const float* __restrict__ bias) {
  constexpr int K = 2048;
  __shared__ __align__(16) char lds[32768];  // A tile 16KB + B tile 16KB
  int t = threadIdx.x;
  int l = t & 63, w = t >> 6;
  int wr = w >> 1, wc = w & 1;
  int l4 = l & 15, lhi = l >> 4;
  size_t rowBase = (size_t)blockIdx.y * 128;
  int colBase = blockIdx.x * 128;

  // staging: 4 calls per matrix, 4KB each (256 thr x 16B). LDS dest linear;
  // global source column pre-swizzled (rule #21) so reads can XOR-deswizzle.
  const char* pA[4];
  const char* pB[4];
  char* ldsA[4];
  char* ldsB[4];
#pragma unroll
  for (int i = 0; i < 4; ++i) {
    int off = i * 4096 + t * 16;   // byte offset within [128][64] bf16 tile
    int r = off >> 7;              // tile row (128B per row)
    int b = off & 127;
    int gb = b ^ ((r & 7) << 4);   // swizzled source byte-in-row
    pA[i] = (const char*)A + ((rowBase + r) * K) * 2 + gb;
    pB[i] = (const char*)BT + (((size_t)colBase + r) * K) * 2 + gb;
    ldsA[i] = lds + i * 4096 + w * 1024;
    ldsB[i] = lds + 16384 + i * 4096 + w * 1024;
  }

  f32x4 acc[4][4];
#pragma unroll
  for (int i = 0; i < 4; ++i)
#pragma unroll
    for (int j = 0; j < 4; ++j) acc[i][j] = (f32x4){0.f, 0.f, 0.f, 0.f};

  // fragment LDS byte offsets (swizzled read): row*128 + ((kk*64+lhi*16)^swz)
  int swz = (l4 & 7) << 4;
  int colp = lhi * 16;
  int aoff[4][2], boff[4][2];
#pragma unroll
  for (int i = 0; i < 4; ++i) {
    int ra = wr * 64 + i * 16 + l4;
    int rb = wc * 64 + i * 16 + l4;
#pragma unroll
    for (int kk = 0; kk < 2; ++kk) {
      aoff[i][kk] = ra * 128 + ((kk * 64 + colp) ^ swz);
      boff[i][kk] = 16384 + rb * 128 + ((kk * 64 + colp) ^ swz);
    }
  }

  for (int kt = 0; kt < K / 64; ++kt) {
#pragma unroll
    for (int i = 0; i < 4; ++i) { gload_lds16(pA[i], ldsA[i]); pA[i] += 128; }
#pragma unroll
    for (int i = 0; i < 4; ++i) { gload_lds16(pB[i], ldsB[i]); pB[i] += 128; }
    __syncthreads();  // compiler drains vmcnt before s_barrier
#pragma unroll
    for (int kk = 0; kk < 2; ++kk) {
      short8 af[4], bfr[4];
#pragma unroll
      for (int i = 0; i < 4; ++i) af[i] = *(const short8*)(lds + aoff[i][kk]);
#pragma unroll
      for (int j = 0; j < 4; ++j) bfr[j] = *(const short8*)(lds + boff[j][kk]);
#pragma unroll
      for (int i = 0; i < 4; ++i)
#pragma unroll
        for (int j = 0; j < 4; ++j)
          acc[i][j] = __builtin_amdgcn_mfma_f32_16x16x32_bf16(af[i], bfr[j],
                                                              acc[i][j], 0, 0, 0);
    }
    __syncthreads();
  }

  // epilogue: C/D map col=lane&15, row=(lane>>4)*4+reg  [m89/m91 verified]
  int lhi4 = lhi * 4;
#pragma unroll
  for (int j = 0; j < 4; ++j) {
    int cc = colBase + wc * 64 + j * 16 + l4;
    float bb = bias[cc];
    float wa = 0.f, wb2 = 0.f, wc3 = 0.f;
    if (MODE == 1) { wa = wex[cc]; wb2 = wex[2048 + cc]; wc3 = wex[4096 + cc]; }
#pragma unroll
    for (int i = 0; i < 4; ++i) {
#pragma unroll
      for (int r = 0; r < 4; ++r) {
        size_t rr = rowBase + wr * 64 + i * 16 + lhi4 + r;
        float v = acc[i][j][r] + bb;
        if (MODE == 1)
          v += feats[rr] * wa + feats[BATCH + rr] * wb2 + feats[2 * BATCH + rr] * wc3;
        v = fmaxf(v, 0.f);
        C[rr * N + cc] = f2bf(v);
      }
    }
  }
}

// ---------------- final GEMV + sigmoid ----------------
__global__ void __launch_bounds__(256) head_kernel(const ushort* __restrict__ S,
                                                   const float* __restrict__ Wr,
                                                   const float* __restrict__ br,
                                                   float* __restrict__ out) {
  int row = blockIdx.x * 4 + (threadIdx.x >> 6);
  int l = threadIdx.x & 63;
  const ushort* s = S + (size_t)row * DIM2 + l * 16;
  const float4* wp = (const float4*)(Wr + l * 16);
  uint4 u0 = *(const uint4*)s;
  uint4 u1 = *(const uint4*)(s + 8);
  float4 w0 = wp[0], w1 = wp[1], w2 = wp[2], w3 = wp[3];
  float sum = 0.f;
  sum += bf2f((ushort)(u0.x & 0xffff)) * w0.x + bf2f((ushort)(u0.x >> 16)) * w0.y;
  sum += bf2f((ushort)(u0.y & 0xffff)) * w0.z + bf2f((ushort)(u0.y >> 16)) * w0.w;
  sum += bf2f((ushort)(u0.z & 0xffff)) * w1.x + bf2f((ushort)(u0.z >> 16)) * w1.y;
  sum += bf2f((ushort)(u0.w & 0xffff)) * w1.z + bf2f((ushort)(u0.w >> 16)) * w1.w;
  sum += bf2f((ushort)(u1.x & 0xffff)) * w2.x + bf2f((ushort)(u1.x >> 16)) * w2.y;
  sum += bf2f((ushort)(u1.y & 0xffff)) * w2.z + bf2f((ushort)(u1.y >> 16)) * w2.w;
  sum += bf2f((ushort)(u1.z & 0xffff)) * w3.x + bf2f((ushort)(u1.z >> 16)) * w3.y;
  sum += bf2f((ushort)(u1.w & 0xffff)) * w3.z + bf2f((ushort)(u1.w >> 16)) * w3.w;
#pragma unroll
  for (int off = 32; off >= 1; off >>= 1) sum += __shfl_down(sum, off, 64);
  if (l == 0) out[row] = 1.f / (1.f + expf(-(sum + br[0])));
}

extern "C" void kernel_launch(void* const* d_in, const int* in_sizes, int n_in,
                              void* d_out, int out_size, void* d_ws, size_t ws_size,
                              hipStream_t stream) {
  const float* h_final = (const float*)d_in[0];
  const float* v_claim = (const float*)d_in[1];
  const float* v_doc   = (const float*)d_in[2];
  const float* W1      = (const float*)d_in[3];
  const float* b1      = (const float*)d_in[4];
  const float* W2      = (const float*)d_in[5];
  const float* b2      = (const float*)d_in[6];
  const float* Wr      = (const float*)d_in[7];
  const float* br      = (const float*)d_in[8];
  float* out = (float*)d_out;

  char* ws = (char*)d_ws;
  ushort* Abf   = (ushort*)ws;                           // 67,108,864 B
  ushort* Hbf   = (ushort*)(ws + 67108864);              // 67,108,864 B
  ushort* W1T   = (ushort*)(ws + 134217728);             //  8,388,608 B
  ushort* W2T   = (ushort*)(ws + 142606336);             //  4,194,304 B
  float*  feats = (float*)(ws + 146800640);              //    196,608 B
  ushort* Sbf   = Abf;  // alias: A operand dead after gemm1

  prep_kernel<<<BATCH, 256, 0, stream>>>(v_claim, v_doc, feats);
  cvt_kernel<<<(BATCH * DIM / 8) / 256, 256, 0, stream>>>(h_final, Abf);
  transW<<<dim3(DIM / 32, DIM / 32), 256, 0, stream>>>(W1, W1T, DIM, DIM);
  transW<<<dim3(DIM2 / 32, DIM / 32), 256, 0, stream>>>(W2, W2T, DIM, DIM2);

  gemm_bt<1, DIM><<<dim3(DIM / 128, BATCH / 128), 256, 0, stream>>>(
      Abf, W1T, Hbf, feats, W1 + (size_t)2048 * 2048, b1);
  gemm_bt<2, DIM2><<<dim3(DIM2 / 128, BATCH / 128), 256, 0, stream>>>(
      Hbf, W2T, Sbf, nullptr, nullptr, b2);

  head_kernel<<<BATCH / 4, 256, 0, stream>>>(Sbf, Wr, br, out);
}

// Round 2
// 396.452 us; speedup vs baseline: 1.2235x; 1.2235x over previous
//
#include <hip/hip_runtime.h>
#include <hip/hip_bf16.h>
#include <stdint.h>

#define BATCH 16384
#define DIM   2048
#define DIM2  1024

typedef __attribute__((ext_vector_type(8))) short short8;
typedef __attribute__((ext_vector_type(4))) float f32x4;

__device__ __forceinline__ ushort f2bf(float f) {
  uint32_t u = __float_as_uint(f);
  u += 0x7fffu + ((u >> 16) & 1u);   // RNE
  return (ushort)(u >> 16);
}
__device__ __forceinline__ float bf2f(ushort h) {
  return __uint_as_float(((uint32_t)h) << 16);
}

__device__ __forceinline__ void gload_lds16(const void* g, void* l) {
  __builtin_amdgcn_global_load_lds(
      (__attribute__((address_space(1))) void*)g,
      (__attribute__((address_space(3))) void*)l,
      16, 0, 0);
}

__device__ __forceinline__ f32x4 MFMA(short8 a, short8 b, f32x4 c) {
  return __builtin_amdgcn_mfma_f32_16x16x32_bf16(a, b, c, 0, 0, 0);
}

// ---------------- per-row cosine features ----------------
__global__ void __launch_bounds__(256) prep_kernel(const float* __restrict__ vc,
                                                   const float* __restrict__ vd,
                                                   float* __restrict__ feats) {
  int row = blockIdx.x;
  int t = threadIdx.x;
  const float4* c = (const float4*)(vc + (size_t)row * DIM);
  const float4* d = (const float4*)(vd + (size_t)row * DIM);
  float dot = 0.f, c2 = 0.f, d2 = 0.f;
#pragma unroll
  for (int p = 0; p < 2; ++p) {
    float4 a = c[t * 2 + p];
    float4 b = d[t * 2 + p];
    dot += a.x * b.x + a.y * b.y + a.z * b.z + a.w * b.w;
    c2  += a.x * a.x + a.y * a.y + a.z * a.z + a.w * a.w;
    d2  += b.x * b.x + b.y * b.y + b.z * b.z + b.w * b.w;
  }
#pragma unroll
  for (int off = 32; off >= 1; off >>= 1) {
    dot += __shfl_down(dot, off, 64);
    c2  += __shfl_down(c2, off, 64);
    d2  += __shfl_down(d2, off, 64);
  }
  __shared__ float red[3][4];
  int l = t & 63, w = t >> 6;
  if (l == 0) { red[0][w] = dot; red[1][w] = c2; red[2][w] = d2; }
  __syncthreads();
  if (t == 0) {
    float D  = red[0][0] + red[0][1] + red[0][2] + red[0][3];
    float C2 = red[1][0] + red[1][1] + red[1][2] + red[1][3];
    float D2 = red[2][0] + red[2][1] + red[2][2] + red[2][3];
    float nc = fmaxf(sqrtf(C2), 1e-12f);
    float nd = fmaxf(sqrtf(D2), 1e-12f);
    float align = D / (nc * nd);
    float dv = 1.f - align;
    feats[row] = align;
    feats[BATCH + row] = dv;
    feats[2 * BATCH + row] = dv * dv;
  }
}

// ---------------- fp32 -> bf16 convert (A operand) ----------------
__global__ void __launch_bounds__(256) cvt_kernel(const float* __restrict__ in,
                                                  ushort* __restrict__ out) {
  size_t i = (size_t)blockIdx.x * 256 + threadIdx.x;  // 8 elems per thread
  const float4* p = (const float4*)in;
  float4 f0 = p[2 * i], f1 = p[2 * i + 1];
  uint4 u;
  u.x = (uint32_t)f2bf(f0.x) | ((uint32_t)f2bf(f0.y) << 16);
  u.y = (uint32_t)f2bf(f0.z) | ((uint32_t)f2bf(f0.w) << 16);
  u.z = (uint32_t)f2bf(f1.x) | ((uint32_t)f2bf(f1.y) << 16);
  u.w = (uint32_t)f2bf(f1.z) | ((uint32_t)f2bf(f1.w) << 16);
  ((uint4*)out)[i] = u;
}

// ---------------- W [K][N] fp32 -> WT [N][K] bf16 ----------------
__global__ void __launch_bounds__(256) transW(const float* __restrict__ W,
                                              ushort* __restrict__ WT,
                                              int K, int N) {
  __shared__ float tile[32][33];
  int t = threadIdx.x;
  int tx = t & 31, ty = t >> 5;
  int c0 = blockIdx.x * 32, r0 = blockIdx.y * 32;
#pragma unroll
  for (int p = 0; p < 4; ++p)
    tile[ty + p * 8][tx] = W[(size_t)(r0 + ty + p * 8) * N + c0 + tx];
  __syncthreads();
#pragma unroll
  for (int p = 0; p < 4; ++p) {
    int rr = ty + p * 8;  // n offset within tile
    WT[(size_t)(c0 + rr) * K + r0 + tx] = f2bf(tile[tx][rr]);
  }
}

// ---------------- 256x256 bf16 MFMA GEMM, 4-phase counted-vmcnt pipeline ----
// C[M][N] = relu(A[M][K] * BT[N][K]^T + rank3 + bias), bf16 out.
// 8 waves (2M x 4N), per-wave 128x64 output (8x4 16x16 frags), BK=64,
// double-buffered 128KB LDS, stage order per next tile: B01,B23,A{0,2},A{1,3};
// waits: p0 vmcnt(2), p2 vmcnt(4)  (vmcnt(0) only on the last tile).
template <int MODE, int N>
__global__ void __launch_bounds__(512, 2) gemm256(const ushort* __restrict__ A,
                                                  const ushort* __restrict__ BT,
                                                  ushort* __restrict__ C,
                                                  const float* __restrict__ feats,
                                                  const float* __restrict__ wex,
                                                  const float* __restrict__ bias) {
  constexpr int K = 2048;
  constexpr int NT = K / 64;  // 32
  __shared__ __align__(16) char lds[131072];
  const int t = threadIdx.x;
  const int l = t & 63, w = t >> 6;
  const int wr = w >> 2, wc = w & 3;
  const int l4 = l & 15, lhi = l >> 4;

  // XCD-aware chunked swizzle (nwg % 8 == 0 for both instantiations)
  const int nwg = gridDim.x;
  const int cpx = nwg >> 3;
  const int bid = blockIdx.x;
  const int swzb = (bid & 7) * cpx + (bid >> 3);
  constexpr int GX = N / 256;
  const int tx = swzb & (GX - 1), ty = swzb / GX;
  const size_t rowBase = (size_t)ty * 256;
  const int colBase = tx * 256;

  // ds_read byte offsets within a buffer (A at 0, B at +32768), XOR-swizzled
  const int swz = (l4 & 7) << 4;
  const int colp = lhi * 16;
  int aoff[8], boff[8];
#pragma unroll
  for (int i = 0; i < 4; ++i) {
    int ra = wr * 128 + i * 16 + l4;
    int rb = wc * 64 + i * 16 + l4;
#pragma unroll
    for (int kk = 0; kk < 2; ++kk) {
      aoff[i * 2 + kk] = ra * 128 + ((kk * 64 + colp) ^ swz);
      boff[i * 2 + kk] = 32768 + rb * 128 + ((kk * 64 + colp) ^ swz);
    }
  }

  // staging source pointers: call c covers tile rows [c*64, c*64+64), 8KB.
  // global column pre-swizzled (rule #21): LDS dest linear, read XOR-deswizzles.
  const char* pA[4];
  const char* pB[4];
#pragma unroll
  for (int c = 0; c < 4; ++c) {
    int off = c * 8192 + t * 16;
    int r = off >> 7;
    int b = off & 127;
    int gb = b ^ ((r & 7) << 4);
    pA[c] = (const char*)A + ((rowBase + r) * K) * 2 + gb;
    pB[c] = (const char*)BT + (((size_t)colBase + r) * K) * 2 + gb;
  }
  const int wB = w * 1024;

  f32x4 acc[8][4];
#pragma unroll
  for (int i = 0; i < 8; ++i)
#pragma unroll
    for (int j = 0; j < 4; ++j) acc[i][j] = (f32x4){0.f, 0.f, 0.f, 0.f};

  // prologue: stage tile 0 into buf0, order B0 B1 | B2 B3 | A0 A2 | A1 A3
  {
    char* nb = lds;
    gload_lds16(pB[0], nb + 32768 + wB);         pB[0] += 128;
    gload_lds16(pB[1], nb + 32768 + 8192 + wB);  pB[1] += 128;
    asm volatile("" ::: "memory");
    gload_lds16(pB[2], nb + 32768 + 16384 + wB); pB[2] += 128;
    gload_lds16(pB[3], nb + 32768 + 24576 + wB); pB[3] += 128;
    asm volatile("" ::: "memory");
    gload_lds16(pA[0], nb + wB);                 pA[0] += 128;
    gload_lds16(pA[2], nb + 16384 + wB);         pA[2] += 128;
    asm volatile("" ::: "memory");
    gload_lds16(pA[1], nb + 8192 + wB);          pA[1] += 128;
    gload_lds16(pA[3], nb + 24576 + wB);         pA[3] += 128;
    asm volatile("" ::: "memory");
  }

  int cur = 0;
  for (int T = 0; T < NT; ++T) {
    char* bufA = lds + cur * 65536;
    char* nb = lds + (cur ^ 1) * 65536;
    const bool pf = (T + 1 < NT);
    short8 aq[8], bq[8];
    // ---------- phase 0 : MFMA (m0-3 x n0-1) ----------
    if (T == NT - 1) asm volatile("s_waitcnt vmcnt(0)" ::: "memory");
    else             asm volatile("s_waitcnt vmcnt(2)" ::: "memory");
    __builtin_amdgcn_s_barrier();
    asm volatile("" ::: "memory");
#pragma unroll
    for (int x = 0; x < 8; ++x) bq[x] = *(const short8*)(bufA + boff[x]);
#pragma unroll
    for (int x = 0; x < 8; ++x) aq[x] = *(const short8*)(bufA + aoff[x]);
    if (pf) {
      gload_lds16(pB[0], nb + 32768 + wB);        pB[0] += 128;
      gload_lds16(pB[1], nb + 32768 + 8192 + wB); pB[1] += 128;
      asm volatile("" ::: "memory");
    }
#pragma unroll
    for (int i = 0; i < 4; ++i)
#pragma unroll
      for (int n = 0; n < 2; ++n)
#pragma unroll
        for (int kk = 0; kk < 2; ++kk)
          acc[i][n] = MFMA(aq[i * 2 + kk], bq[n * 2 + kk], acc[i][n]);
    // ---------- phase 1 : MFMA (m0-3 x n2-3) ----------
    if (pf) {
      gload_lds16(pB[2], nb + 32768 + 16384 + wB); pB[2] += 128;
      gload_lds16(pB[3], nb + 32768 + 24576 + wB); pB[3] += 128;
      asm volatile("" ::: "memory");
    }
#pragma unroll
    for (int i = 0; i < 4; ++i)
#pragma unroll
      for (int n = 2; n < 4; ++n)
#pragma unroll
        for (int kk = 0; kk < 2; ++kk)
          acc[i][n] = MFMA(aq[i * 2 + kk], bq[n * 2 + kk], acc[i][n]);
    // ---------- phase 2 : MFMA (m4-7 x n0-1) ----------
    if (T == NT - 1) asm volatile("s_waitcnt vmcnt(0)" ::: "memory");
    else             asm volatile("s_waitcnt vmcnt(4)" ::: "memory");
    __builtin_amdgcn_s_barrier();
    asm volatile("" ::: "memory");
#pragma unroll
    for (int x = 0; x < 8; ++x) aq[x] = *(const short8*)(bufA + 8192 + aoff[x]);
    if (pf) {
      gload_lds16(pA[0], nb + wB);         pA[0] += 128;
      gload_lds16(pA[2], nb + 16384 + wB); pA[2] += 128;
      asm volatile("" ::: "memory");
    }
#pragma unroll
    for (int i = 0; i < 4; ++i)
#pragma unroll
      for (int n = 0; n < 2; ++n)
#pragma unroll
        for (int kk = 0; kk < 2; ++kk)
          acc[4 + i][n] = MFMA(aq[i * 2 + kk], bq[n * 2 + kk], acc[4 + i][n]);
    // ---------- phase 3 : MFMA (m4-7 x n2-3) ----------
    if (pf) {
      gload_lds16(pA[1], nb + 8192 + wB);  pA[1] += 128;
      gload_lds16(pA[3], nb + 24576 + wB); pA[3] += 128;
      asm volatile("" ::: "memory");
    }
#pragma unroll
    for (int i = 0; i < 4; ++i)
#pragma unroll
      for (int n = 2; n < 4; ++n)
#pragma unroll
        for (int kk = 0; kk < 2; ++kk)
          acc[4 + i][n] = MFMA(aq[i * 2 + kk], bq[n * 2 + kk], acc[4 + i][n]);
    cur ^= 1;
  }

  // epilogue: C/D map col=lane&15, row=(lane>>4)*4+reg  [m89/m91 verified]
  const int lhi4 = lhi * 4;
#pragma unroll
  for (int n = 0; n < 4; ++n) {
    int cc = colBase + wc * 64 + n * 16 + l4;
    float bb = bias[cc];
    float wa = 0.f, wb2 = 0.f, wc3 = 0.f;
    if (MODE == 1) { wa = wex[cc]; wb2 = wex[2048 + cc]; wc3 = wex[4096 + cc]; }
#pragma unroll
    for (int m = 0; m < 8; ++m) {
#pragma unroll
      for (int r = 0; r < 4; ++r) {
        size_t rr = rowBase + wr * 128 + m * 16 + lhi4 + r;
        float v = acc[m][n][r] + bb;
        if (MODE == 1)
          v += feats[rr] * wa + feats[BATCH + rr] * wb2 + feats[2 * BATCH + rr] * wc3;
        v = fmaxf(v, 0.f);
        C[rr * N + cc] = f2bf(v);
      }
    }
  }
}

// ---------------- final GEMV + sigmoid ----------------
__global__ void __launch_bounds__(256) head_kernel(const ushort* __restrict__ S,
                                                   const float* __restrict__ Wr,
                                                   const float* __restrict__ br,
                                                   float* __restrict__ out) {
  int row = blockIdx.x * 4 + (threadIdx.x >> 6);
  int l = threadIdx.x & 63;
  const ushort* s = S + (size_t)row * DIM2 + l * 16;
  const float4* wp = (const float4*)(Wr + l * 16);
  uint4 u0 = *(const uint4*)s;
  uint4 u1 = *(const uint4*)(s + 8);
  float4 w0 = wp[0], w1 = wp[1], w2 = wp[2], w3 = wp[3];
  float sum = 0.f;
  sum += bf2f((ushort)(u0.x & 0xffff)) * w0.x + bf2f((ushort)(u0.x >> 16)) * w0.y;
  sum += bf2f((ushort)(u0.y & 0xffff)) * w0.z + bf2f((ushort)(u0.y >> 16)) * w0.w;
  sum += bf2f((ushort)(u0.z & 0xffff)) * w1.x + bf2f((ushort)(u0.z >> 16)) * w1.y;
  sum += bf2f((ushort)(u0.w & 0xffff)) * w1.z + bf2f((ushort)(u0.w >> 16)) * w1.w;
  sum += bf2f((ushort)(u1.x & 0xffff)) * w2.x + bf2f((ushort)(u1.x >> 16)) * w2.y;
  sum += bf2f((ushort)(u1.y & 0xffff)) * w2.z + bf2f((ushort)(u1.y >> 16)) * w2.w;
  sum += bf2f((ushort)(u1.z & 0xffff)) * w3.x + bf2f((ushort)(u1.z >> 16)) * w3.y;
  sum += bf2f((ushort)(u1.w & 0xffff)) * w3.z + bf2f((ushort)(u1.w >> 16)) * w3.w;
#pragma unroll
  for (int off = 32; off >= 1; off >>= 1) sum += __shfl_down(sum, off, 64);
  if (l == 0) out[row] = 1.f / (1.f + expf(-(sum + br[0])));
}

extern "C" void kernel_launch(void* const* d_in, const int* in_sizes, int n_in,
                              void* d_out, int out_size, void* d_ws, size_t ws_size,
                              hipStream_t stream) {
  const float* h_final = (const float*)d_in[0];
  const float* v_claim = (const float*)d_in[1];
  const float* v_doc   = (const float*)d_in[2];
  const float* W1      = (const float*)d_in[3];
  const float* b1      = (const float*)d_in[4];
  const float* W2      = (const float*)d_in[5];
  const float* b2      = (const float*)d_in[6];
  const float* Wr      = (const float*)d_in[7];
  const float* br      = (const float*)d_in[8];
  float* out = (float*)d_out;

  char* ws = (char*)d_ws;
  ushort* Abf   = (ushort*)ws;                           // 67,108,864 B
  ushort* Hbf   = (ushort*)(ws + 67108864);              // 67,108,864 B
  ushort* W1T   = (ushort*)(ws + 134217728);             //  8,388,608 B
  ushort* W2T   = (ushort*)(ws + 142606336);             //  4,194,304 B
  float*  feats = (float*)(ws + 146800640);              //    196,608 B
  ushort* Sbf   = Abf;  // alias: A operand dead after gemm1

  prep_kernel<<<BATCH, 256, 0, stream>>>(v_claim, v_doc, feats);
  cvt_kernel<<<(BATCH * DIM / 8) / 256, 256, 0, stream>>>(h_final, Abf);
  transW<<<dim3(DIM / 32, DIM / 32), 256, 0, stream>>>(W1, W1T, DIM, DIM);
  transW<<<dim3(DIM2 / 32, DIM / 32), 256, 0, stream>>>(W2, W2T, DIM, DIM2);

  gemm256<1, DIM><<<(DIM / 256) * (BATCH / 256), 512, 0, stream>>>(
      Abf, W1T, Hbf, feats, W1 + (size_t)2048 * 2048, b1);
  gemm256<2, DIM2><<<(DIM2 / 256) * (BATCH / 256), 512, 0, stream>>>(
      Hbf, W2T, Sbf, nullptr, nullptr, b2);

  head_kernel<<<BATCH / 4, 256, 0, stream>>>(Sbf, Wr, br, out);
}

// Round 3
// 289.745 us; speedup vs baseline: 1.6741x; 1.3683x over previous
//
#include <hip/hip_runtime.h>
#include <hip/hip_bf16.h>
#include <stdint.h>

#define BATCH 16384
#define DIM   2048
#define DIM2  1024

typedef __attribute__((ext_vector_type(8))) short short8;
typedef __attribute__((ext_vector_type(4))) float f32x4;

__device__ __forceinline__ ushort f2bf(float f) {
  uint32_t u = __float_as_uint(f);
  u += 0x7fffu + ((u >> 16) & 1u);   // RNE
  return (ushort)(u >> 16);
}
__device__ __forceinline__ float bf2f(ushort h) {
  return __uint_as_float(((uint32_t)h) << 16);
}

__device__ __forceinline__ void gload_lds16(const void* g, void* l) {
  __builtin_amdgcn_global_load_lds(
      (__attribute__((address_space(1))) void*)g,
      (__attribute__((address_space(3))) void*)l,
      16, 0, 0);
}

__device__ __forceinline__ f32x4 MFMA(short8 a, short8 b, f32x4 c) {
  return __builtin_amdgcn_mfma_f32_16x16x32_bf16(a, b, c, 0, 0, 0);
}

// ---------------- per-row cosine features ----------------
__global__ void __launch_bounds__(256) prep_kernel(const float* __restrict__ vc,
                                                   const float* __restrict__ vd,
                                                   float* __restrict__ feats) {
  int row = blockIdx.x;
  int t = threadIdx.x;
  const float4* c = (const float4*)(vc + (size_t)row * DIM);
  const float4* d = (const float4*)(vd + (size_t)row * DIM);
  float dot = 0.f, c2 = 0.f, d2 = 0.f;
#pragma unroll
  for (int p = 0; p < 2; ++p) {
    float4 a = c[t * 2 + p];
    float4 b = d[t * 2 + p];
    dot += a.x * b.x + a.y * b.y + a.z * b.z + a.w * b.w;
    c2  += a.x * a.x + a.y * a.y + a.z * a.z + a.w * a.w;
    d2  += b.x * b.x + b.y * b.y + b.z * b.z + b.w * b.w;
  }
#pragma unroll
  for (int off = 32; off >= 1; off >>= 1) {
    dot += __shfl_down(dot, off, 64);
    c2  += __shfl_down(c2, off, 64);
    d2  += __shfl_down(d2, off, 64);
  }
  __shared__ float red[3][4];
  int l = t & 63, w = t >> 6;
  if (l == 0) { red[0][w] = dot; red[1][w] = c2; red[2][w] = d2; }
  __syncthreads();
  if (t == 0) {
    float D  = red[0][0] + red[0][1] + red[0][2] + red[0][3];
    float C2 = red[1][0] + red[1][1] + red[1][2] + red[1][3];
    float D2 = red[2][0] + red[2][1] + red[2][2] + red[2][3];
    float nc = fmaxf(sqrtf(C2), 1e-12f);
    float nd = fmaxf(sqrtf(D2), 1e-12f);
    float align = D / (nc * nd);
    float dv = 1.f - align;
    feats[row] = align;
    feats[BATCH + row] = dv;
    feats[2 * BATCH + row] = dv * dv;
  }
}

// ---------------- fp32 -> bf16 convert (A operand) ----------------
__global__ void __launch_bounds__(256) cvt_kernel(const float* __restrict__ in,
                                                  ushort* __restrict__ out) {
  size_t i = (size_t)blockIdx.x * 256 + threadIdx.x;  // 8 elems per thread
  const float4* p = (const float4*)in;
  float4 f0 = p[2 * i], f1 = p[2 * i + 1];
  uint4 u;
  u.x = (uint32_t)f2bf(f0.x) | ((uint32_t)f2bf(f0.y) << 16);
  u.y = (uint32_t)f2bf(f0.z) | ((uint32_t)f2bf(f0.w) << 16);
  u.z = (uint32_t)f2bf(f1.x) | ((uint32_t)f2bf(f1.y) << 16);
  u.w = (uint32_t)f2bf(f1.z) | ((uint32_t)f2bf(f1.w) << 16);
  ((uint4*)out)[i] = u;
}

// ---------------- W [K][N] fp32 -> WT [N][K] bf16 ----------------
__global__ void __launch_bounds__(256) transW(const float* __restrict__ W,
                                              ushort* __restrict__ WT,
                                              int K, int N) {
  __shared__ float tile[32][33];
  int t = threadIdx.x;
  int tx = t & 31, ty = t >> 5;
  int c0 = blockIdx.x * 32, r0 = blockIdx.y * 32;
#pragma unroll
  for (int p = 0; p < 4; ++p)
    tile[ty + p * 8][tx] = W[(size_t)(r0 + ty + p * 8) * N + c0 + tx];
  __syncthreads();
#pragma unroll
  for (int p = 0; p < 4; ++p) {
    int rr = ty + p * 8;  // n offset within tile
    WT[(size_t)(c0 + rr) * K + r0 + tx] = f2bf(tile[tx][rr]);
  }
}

// ---------------- 256x256 bf16 MFMA GEMM, 8-phase K-half slot ring ---------
// 8 waves (2M x 4N), per-wave 128x64 out (8x4 frags). K-step 64 split in two
// K-half slots of 16KB: [128 lds-rows][128B] = (row-half hb, 64B) packed, XOR
// swizzle byte^=(row&7)<<4 on both stage-source and read (rule #21).
// 8 slots: [tile-parity][{A,B}][{k0,k1}]. One slot staged per phase (2
// gload_lds of 8KB), read 6 phases later. vmcnt(8) at odd-phase close only.
template <int MODE, int N>
__global__ void __launch_bounds__(512, 1) gemm256(const ushort* __restrict__ A,
                                                  const ushort* __restrict__ BT,
                                                  ushort* __restrict__ C,
                                                  const float* __restrict__ feats,
                                                  const float* __restrict__ wex,
                                                  const float* __restrict__ bias) {
  constexpr int K = 2048;
  constexpr int NT = K / 64;   // 32 K-tiles, 16 iterations x 2 tiles
  __shared__ __align__(16) char lds[131072];
  const int tid = threadIdx.x;
  const int l = tid & 63, w = tid >> 6;
  const int wr = w >> 2, wc = w & 3;
  const int l4 = l & 15, lhi = l >> 4;

  constexpr int GX = N / 256;
  const int bid = blockIdx.x;
  const int tx = bid % GX, ty = bid / GX;  // GX=8: tx == XCD -> B L2-resident
  const size_t rowBase = (size_t)ty * 256;
  const int colBase = tx * 256;

  // ds_read offsets (within a 16KB slot)
  const int swz = (l4 & 7) << 4;
  const int aoffBase = l4 * 128 + ((wr * 64 + lhi * 16) ^ swz);
  const int boffBase = ((wc & 1) * 64 + l4) * 128 + (((wc >> 1) * 64 + lhi * 16) ^ swz);

  // stage source pointers: LDS offset o = c*8192 + tid*16 decodes as
  // lds-row r = o>>7, byte-in-row b0 = o&127; source = inverse-swizzle of b0.
  const char* pAs[2];
  const char* pBs[2];
#pragma unroll
  for (int c = 0; c < 2; ++c) {
    int o = c * 8192 + tid * 16;
    int r = o >> 7, b0 = o & 127;
    int bsw = b0 ^ ((r & 7) << 4);
    int hb = bsw >> 6, cb = bsw & 63;
    pAs[c] = (const char*)A + (rowBase + hb * 128 + r) * (2 * K) + cb;
    pBs[c] = (const char*)BT + ((size_t)colBase + hb * 128 + r) * (2 * K) + cb;
  }
  const int ldso0 = w * 1024;
  const int ldso1 = 8192 + w * 1024;

#define STAGE(srcT, destPar, M, kh)                                          \
  do {                                                                       \
    char* dst_ = lds + (destPar) * 65536 + (kh) * 32768 + (M) * 16384;       \
    const char* s0_ = ((M) ? pBs[0] : pAs[0]) + (srcT) * 128 + (kh) * 64;    \
    const char* s1_ = ((M) ? pBs[1] : pAs[1]) + (srcT) * 128 + (kh) * 64;    \
    gload_lds16(s0_, dst_ + ldso0);                                          \
    gload_lds16(s1_, dst_ + ldso1);                                          \
    asm volatile("" ::: "memory");                                           \
  } while (0)

#define LOADA(q, d, kh)                                                      \
  do {                                                                       \
    const char* sb_ = lds + (d) * 65536 + (kh) * 32768;                      \
    aq[0] = *(const short8*)(sb_ + ((q) * 4 + 0) * 2048 + aoffBase);         \
    aq[1] = *(const short8*)(sb_ + ((q) * 4 + 1) * 2048 + aoffBase);         \
    aq[2] = *(const short8*)(sb_ + ((q) * 4 + 2) * 2048 + aoffBase);         \
    aq[3] = *(const short8*)(sb_ + ((q) * 4 + 3) * 2048 + aoffBase);         \
  } while (0)

#define LOADB(d, kh)                                                         \
  do {                                                                       \
    const char* sb_ = lds + (d) * 65536 + (kh) * 32768 + 16384;              \
    bq[0] = *(const short8*)(sb_ + 0 * 2048 + boffBase);                     \
    bq[1] = *(const short8*)(sb_ + 1 * 2048 + boffBase);                     \
    bq[2] = *(const short8*)(sb_ + 2 * 2048 + boffBase);                     \
    bq[3] = *(const short8*)(sb_ + 3 * 2048 + boffBase);                     \
  } while (0)

#define MF(q)                                                                \
  do {                                                                       \
    _Pragma("unroll") for (int j_ = 0; j_ < 4; ++j_)                         \
        _Pragma("unroll") for (int n_ = 0; n_ < 4; ++n_)                     \
            acc[(q) * 4 + j_][n_] = MFMA(aq[j_], bq[n_], acc[(q) * 4 + j_][n_]); \
  } while (0)

#define BAR()     __builtin_amdgcn_s_barrier()
#define LGKM0()   asm volatile("s_waitcnt lgkmcnt(0)" ::: "memory")
#define VM8()     asm volatile("s_waitcnt vmcnt(8)" ::: "memory")
#define PRIO(x)   __builtin_amdgcn_s_setprio(x)

  f32x4 acc[8][4];
#pragma unroll
  for (int i = 0; i < 8; ++i)
#pragma unroll
    for (int j = 0; j < 4; ++j) acc[i][j] = (f32x4){0.f, 0.f, 0.f, 0.f};

  // prologue: 6 slots, 12 loads; then guard first two slots (vmcnt(8))
  STAGE(0, 0, 0, 0);
  STAGE(0, 0, 1, 0);
  STAGE(0, 0, 0, 1);
  STAGE(0, 0, 1, 1);
  STAGE(1, 1, 0, 0);
  STAGE(1, 1, 1, 0);
  VM8();
  BAR();

  for (int I = 0; I < NT / 2; ++I) {
    const int o = 2 * I + 1;
    const int e2 = (2 * I + 2 < NT) ? 2 * I + 2 : 0;   // src clamp (uniform counts)
    const int o2 = (2 * I + 3 < NT) ? 2 * I + 3 : 0;
    short8 aq[4], bq[4];
    // ---- p0: tile e, k0, q0 ----
    LOADB(0, 0);
    LOADA(0, 0, 0);
    STAGE(o, 1, 0, 1);
    BAR(); LGKM0();
    PRIO(1); MF(0); PRIO(0);
    BAR();
    // ---- p1: tile e, k0, q1 ----
    LOADA(1, 0, 0);
    STAGE(o, 1, 1, 1);
    BAR(); LGKM0();
    PRIO(1); MF(1); PRIO(0);
    VM8();
    BAR();
    // ---- p2: tile e, k1, q0 ----
    LOADB(0, 1);
    LOADA(0, 0, 1);
    STAGE(e2, 0, 0, 0);
    BAR(); LGKM0();
    PRIO(1); MF(0); PRIO(0);
    BAR();
    // ---- p3: tile e, k1, q1 ----
    LOADA(1, 0, 1);
    STAGE(e2, 0, 1, 0);
    BAR(); LGKM0();
    PRIO(1); MF(1); PRIO(0);
    VM8();
    BAR();
    // ---- p4: tile o, k0, q0 ----
    LOADB(1, 0);
    LOADA(0, 1, 0);
    STAGE(e2, 0, 0, 1);
    BAR(); LGKM0();
    PRIO(1); MF(0); PRIO(0);
    BAR();
    // ---- p5: tile o, k0, q1 ----
    LOADA(1, 1, 0);
    STAGE(e2, 0, 1, 1);
    BAR(); LGKM0();
    PRIO(1); MF(1); PRIO(0);
    VM8();
    BAR();
    // ---- p6: tile o, k1, q0 ----
    LOADB(1, 1);
    LOADA(0, 1, 1);
    STAGE(o2, 1, 0, 0);
    BAR(); LGKM0();
    PRIO(1); MF(0); PRIO(0);
    BAR();
    // ---- p7: tile o, k1, q1 ----
    LOADA(1, 1, 1);
    STAGE(o2, 1, 1, 0);
    BAR(); LGKM0();
    PRIO(1); MF(1); PRIO(0);
    VM8();
    BAR();
  }
  asm volatile("s_waitcnt vmcnt(0)" ::: "memory");

  // epilogue: C/D map col=lane&15, row=(lane>>4)*4+reg  [m89/m91 verified]
  // n-inner so each 128B row-segment is dirtied by 4 consecutive stores.
  int ccv[4];
  float bb[4], wa[4], wb2[4], wc3[4];
#pragma unroll
  for (int n = 0; n < 4; ++n) {
    int cc = colBase + wc * 64 + n * 16 + l4;
    ccv[n] = cc;
    bb[n] = bias[cc];
    if (MODE == 1) {
      wa[n] = wex[cc]; wb2[n] = wex[2048 + cc]; wc3[n] = wex[4096 + cc];
    } else {
      wa[n] = 0.f; wb2[n] = 0.f; wc3[n] = 0.f;
    }
  }
  const int lhi4 = lhi * 4;
#pragma unroll
  for (int m = 0; m < 8; ++m) {
#pragma unroll
    for (int r = 0; r < 4; ++r) {
      size_t rr = rowBase + wr * 128 + m * 16 + lhi4 + r;
      float f1 = 0.f, f2 = 0.f, f3 = 0.f;
      if (MODE == 1) {
        f1 = feats[rr]; f2 = feats[BATCH + rr]; f3 = feats[2 * BATCH + rr];
      }
#pragma unroll
      for (int n = 0; n < 4; ++n) {
        float v = acc[m][n][r] + bb[n];
        if (MODE == 1) v += f1 * wa[n] + f2 * wb2[n] + f3 * wc3[n];
        v = fmaxf(v, 0.f);
        C[rr * N + ccv[n]] = f2bf(v);
      }
    }
  }
#undef STAGE
#undef LOADA
#undef LOADB
#undef MF
#undef BAR
#undef LGKM0
#undef VM8
#undef PRIO
}

// ---------------- final GEMV + sigmoid ----------------
__global__ void __launch_bounds__(256) head_kernel(const ushort* __restrict__ S,
                                                   const float* __restrict__ Wr,
                                                   const float* __restrict__ br,
                                                   float* __restrict__ out) {
  int row = blockIdx.x * 4 + (threadIdx.x >> 6);
  int l = threadIdx.x & 63;
  const ushort* s = S + (size_t)row * DIM2 + l * 16;
  const float4* wp = (const float4*)(Wr + l * 16);
  uint4 u0 = *(const uint4*)s;
  uint4 u1 = *(const uint4*)(s + 8);
  float4 w0 = wp[0], w1 = wp[1], w2 = wp[2], w3 = wp[3];
  float sum = 0.f;
  sum += bf2f((ushort)(u0.x & 0xffff)) * w0.x + bf2f((ushort)(u0.x >> 16)) * w0.y;
  sum += bf2f((ushort)(u0.y & 0xffff)) * w0.z + bf2f((ushort)(u0.y >> 16)) * w0.w;
  sum += bf2f((ushort)(u0.z & 0xffff)) * w1.x + bf2f((ushort)(u0.z >> 16)) * w1.y;
  sum += bf2f((ushort)(u0.w & 0xffff)) * w1.z + bf2f((ushort)(u0.w >> 16)) * w1.w;
  sum += bf2f((ushort)(u1.x & 0xffff)) * w2.x + bf2f((ushort)(u1.x >> 16)) * w2.y;
  sum += bf2f((ushort)(u1.y & 0xffff)) * w2.z + bf2f((ushort)(u1.y >> 16)) * w2.w;
  sum += bf2f((ushort)(u1.z & 0xffff)) * w3.x + bf2f((ushort)(u1.z >> 16)) * w3.y;
  sum += bf2f((ushort)(u1.w & 0xffff)) * w3.z + bf2f((ushort)(u1.w >> 16)) * w3.w;
#pragma unroll
  for (int off = 32; off >= 1; off >>= 1) sum += __shfl_down(sum, off, 64);
  if (l == 0) out[row] = 1.f / (1.f + expf(-(sum + br[0])));
}

extern "C" void kernel_launch(void* const* d_in, const int* in_sizes, int n_in,
                              void* d_out, int out_size, void* d_ws, size_t ws_size,
                              hipStream_t stream) {
  const float* h_final = (const float*)d_in[0];
  const float* v_claim = (const float*)d_in[1];
  const float* v_doc   = (const float*)d_in[2];
  const float* W1      = (const float*)d_in[3];
  const float* b1      = (const float*)d_in[4];
  const float* W2      = (const float*)d_in[5];
  const float* b2      = (const float*)d_in[6];
  const float* Wr      = (const float*)d_in[7];
  const float* br      = (const float*)d_in[8];
  float* out = (float*)d_out;

  char* ws = (char*)d_ws;
  ushort* Abf   = (ushort*)ws;                           // 67,108,864 B
  ushort* Hbf   = (ushort*)(ws + 67108864);              // 67,108,864 B
  ushort* W1T   = (ushort*)(ws + 134217728);             //  8,388,608 B
  ushort* W2T   = (ushort*)(ws + 142606336);             //  4,194,304 B
  float*  feats = (float*)(ws + 146800640);              //    196,608 B
  ushort* Sbf   = Abf;  // alias: A operand dead after gemm1

  prep_kernel<<<BATCH, 256, 0, stream>>>(v_claim, v_doc, feats);
  cvt_kernel<<<(BATCH * DIM / 8) / 256, 256, 0, stream>>>(h_final, Abf);
  transW<<<dim3(DIM / 32, DIM / 32), 256, 0, stream>>>(W1, W1T, DIM, DIM);
  transW<<<dim3(DIM2 / 32, DIM / 32), 256, 0, stream>>>(W2, W2T, DIM, DIM2);

  gemm256<1, DIM><<<(DIM / 256) * (BATCH / 256), 512, 0, stream>>>(
      Abf, W1T, Hbf, feats, W1 + (size_t)2048 * 2048, b1);
  gemm256<2, DIM2><<<(DIM2 / 256) * (BATCH / 256), 512, 0, stream>>>(
      Hbf, W2T, Sbf, nullptr, nullptr, b2);

  head_kernel<<<BATCH / 4, 256, 0, stream>>>(Sbf, Wr, br, out);
}